// Round 3
// baseline (203.171 us; speedup 1.0000x reference)
//
#include <hip/hip_runtime.h>

// Gridding R8: R7 (174.7 µs) + wave-aggregated slab counters in p1.
//   R7 counters: p2 = 82.4 µs == the packed-u64 LDS-atomic-pipe floor
//   (16.8M lane-atomics x 3.25 cyc / 256 CU = 89 µs model). Remaining
//   budget is p1 (~75-90 µs), whose memory is only ~14 µs -> it is bound
//   by per-lane LDS counter atomics (64 lanes -> 16 addresses, pure
//   lane-rate serialization) + scattered slot writes. This round: per-wave
//   ballot aggregation -- for each of the 16 slabs, one leader atomicAdd
//   reserves a contiguous range and lanes self-place via mbcnt rank.
//   Counter lane-atomics drop 80 -> 16 per 64 points (~20 µs of pipe).
//   p2: chunk counts cached in LDS (kills 8K redundant global re-reads).
//   Everything else (packed u64 staging, rescan self-healing, fallback)
//   unchanged from the passing R7.

#define NPTS   65536
#define NCHUNK 32
#define CHSZ   2048
#define NSLAB  16                  // p1 bucket slabs (4 planes)
#define SLABW  4
#define CCAP   256
#define SLOTS  (NCHUNK * CCAP)     // 8192 slots per bucket
#define ACCN   16384               // 2 planes * 64 * 64 u32 per accumulator
#define QSCALE 262144.0f           // 2^18 weight quant
#define QINV   (1.0f / 262144.0f)
#define CMASK  0x1FFFFFu           // 21-bit coordinate field
#define FSCALE 32768.0f            // 2^15 coordinate quant
#define FINV   (1.0f / 32768.0f)

__device__ __forceinline__ int lane_rank(unsigned long long m) {
    // popcount of m restricted to lanes below this one
    return __builtin_amdgcn_mbcnt_hi((unsigned)(m >> 32),
           __builtin_amdgcn_mbcnt_lo((unsigned)m, 0));
}

// ---------------- Phase 1: bin points, wave-aggregated counters ----------
__global__ __launch_bounds__(512) void p1_bin(
    const float* __restrict__ pt,
    unsigned long long* __restrict__ gp,
    int* __restrict__ bcnt)
{
    __shared__ unsigned long long spk[NSLAB * CCAP];   // 32 KB
    __shared__ int cnt[NSLAB];
    if (threadIdx.x < NSLAB) cnt[threadIdx.x] = 0;
    __syncthreads();

    const int blk = blockIdx.x;
    const int b = blk >> 5;
    const int c = blk & 31;
    const float* p = pt + ((size_t)b * NPTS + (size_t)c * CHSZ) * 3;

    for (int k = 0; k < CHSZ / 512; ++k) {
        int li = k * 512 + threadIdx.x;
        float px = p[3 * li + 0] * 32.0f;
        float py = p[3 * li + 1] * 32.0f;
        float pz = p[3 * li + 2] * 32.0f;
        bool valid = (fabsf(px) + fabsf(py) + fabsf(pz) != 0.0f);
        // grid-space [0,64) fixed point, round-to-nearest, clamped to the
        // 21-bit field. v_cvt_u32 saturates negatives to 0 -> ix in [0,63].
        unsigned ux = min(__float2uint_rn((px + 32.0f) * FSCALE), CMASK);
        unsigned uy = min(__float2uint_rn((py + 32.0f) * FSCALE), CMASK);
        unsigned uz = min(__float2uint_rn((pz + 32.0f) * FSCALE), CMASK);
        int ix = (int)(ux >> 15);
        unsigned long long pk =
            (unsigned long long)ux | ((unsigned long long)uy << 21)
                                   | ((unsigned long long)uz << 42);
        int s0 = ix >> 2;
        bool dup = valid && ((ix & 3) == 3) && (ix < 63);

        #pragma unroll 1
        for (int s = 0; s < NSLAB; ++s) {
            unsigned long long m0 = __ballot(valid && (s0 == s));
            unsigned long long m1 = __ballot(dup && (s0 + 1 == s));
            if ((m0 | m1) == 0ull) continue;          // uniform branch
            int nadd = __popcll(m0) + __popcll(m1);
            int base = 0;
            if ((threadIdx.x & 63) == 0) base = atomicAdd(&cnt[s], nadd);
            base = __shfl(base, 0, 64);
            if (valid && s0 == s) {
                int pos = base + lane_rank(m0);
                if (pos < CCAP) spk[s * CCAP + pos] = pk;
            }
            if (dup && (s0 + 1 == s)) {
                int pos = base + __popcll(m0) + lane_rank(m1);
                if (pos < CCAP) spk[s * CCAP + pos] = pk;
            }
        }
    }
    __syncthreads();

    // Flush only the counted slots (garbage slots never touch HBM).
    #pragma unroll
    for (int i = threadIdx.x; i < NSLAB * CCAP; i += 512) {
        int s = i >> 8, e = i & 255;
        if (e < min(cnt[s], CCAP)) {
            size_t d = ((size_t)((b * NSLAB + s) * NCHUNK + c)) * CCAP + e;
            gp[d] = spk[i];
        }
    }
    if (threadIdx.x < NSLAB)
        bcnt[(b * NSLAB + threadIdx.x) * NCHUNK + c] = min(cnt[threadIdx.x], CCAP);
}

// Shared corner accumulation (packed u64 LDS atomics), grid-space coords.
//   S[0..ACCN)      = A: cell (xl,y,z) at (xl*64+y)*64+z   (z-even u64 pairs)
//   S[ACCN..2*ACCN) = B: shifted pairs (z-odd), B[cb+z-1],B[cb+z]
__device__ __forceinline__ void accum_corners(
    unsigned int* S, int ix, int iy, int iz,
    float fx, float fy, float fz, int x0)
{
    if ((unsigned)iz > 63u) return;     // OOB z (garbage guard)

    float wx[2] = {1.0f - fx, fx};
    float wy[2] = {1.0f - fy, fy};
    float wz0 = 1.0f - fz, wz1 = fz;

    const int odd = iz & 1;
    const int zoff = odd ? (ACCN + iz - 1) : iz;   // both branches 8B-aligned
    const bool hi_ok = (iz != 63);                 // cell iz+1==64 OOB -> add 0

    #pragma unroll
    for (int di = 0; di < 2; ++di) {
        int xl = ix + di - x0;              // sub-slab-local x
        if ((unsigned)xl >= 2u) continue;
        #pragma unroll
        for (int dj = 0; dj < 2; ++dj) {
            int yy = iy + dj;
            if ((unsigned)yy >= 64u) continue;
            float wxy = wx[di] * wy[dj];
            unsigned int q0 = __float2uint_rn(wxy * wz0 * QSCALE);
            unsigned int q1 = hi_ok ? __float2uint_rn(wxy * wz1 * QSCALE) : 0u;
            int cb = (xl * 64 + yy) * 64;
            unsigned long long pk =
                (unsigned long long)q0 | ((unsigned long long)q1 << 32);
            atomicAdd((unsigned long long*)&S[cb + zoff], pk);  // ds_add_u64
        }
    }
}

// ---------------- Phase 2: 2-plane sub-slab, packed u64 LDS atomics -------
__global__ __launch_bounds__(1024) void p2_accum(
    const unsigned long long* __restrict__ gp, const int* __restrict__ bcnt,
    const float* __restrict__ pt, float* __restrict__ out)
{
    __shared__ unsigned int S[2 * ACCN];
    __shared__ int scnt[NCHUNK];
    __shared__ int rescan;

    const int pb = blockIdx.x >> 1;     // parent bucket (b*16 + s)
    const int h  = blockIdx.x & 1;      // which half of the 4-wide slab
    const int b  = pb >> 4;
    const int s  = pb & 15;
    const int x0 = s * SLABW + h * 2;   // my 2 planes: x0, x0+1

    if (threadIdx.x == 0) rescan = 0;
    if (threadIdx.x < NCHUNK)
        scnt[threadIdx.x] = bcnt[pb * NCHUNK + threadIdx.x];
    uint4* s4 = (uint4*)S;
    #pragma unroll
    for (int i = threadIdx.x; i < (2 * ACCN) / 4; i += 1024)
        s4[i] = make_uint4(0u, 0u, 0u, 0u);
    __syncthreads();

    // Saturation / sanity check: CCAP sentinel (p1 dropped points) or
    // garbage counts -> this block redoes its sub-slab from raw points.
    if (threadIdx.x < NCHUNK) {
        if ((unsigned)scnt[threadIdx.x] >= (unsigned)CCAP) rescan = 1;
    }
    __syncthreads();

    if (!rescan) {
        // ---- fast path: decode packed u64 points ----
        const size_t base = (size_t)pb * SLOTS;

        #pragma unroll
        for (int t = threadIdx.x; t < SLOTS; t += 1024) {
            int c = t >> 8;                 // CCAP = 256
            int pos = t & 255;
            if (pos >= scnt[c]) continue;
            unsigned long long pk = gp[base + t];
            unsigned ux = (unsigned)pk & CMASK;
            unsigned uy = (unsigned)(pk >> 21) & CMASK;
            unsigned uz = (unsigned)(pk >> 42) & CMASK;
            accum_corners(S, (int)(ux >> 15), (int)(uy >> 15), (int)(uz >> 15),
                          (float)(ux & 32767u) * FINV,
                          (float)(uy & 32767u) * FINV,
                          (float)(uz & 32767u) * FINV, x0);
        }
    } else {
        // ---- self-healing path: exclusive scan of batch b's raw points ----
        const float* p = pt + (size_t)b * NPTS * 3;
        for (int i = threadIdx.x; i < NPTS; i += 1024) {
            float px = p[3 * i + 0] * 32.0f;
            float py = p[3 * i + 1] * 32.0f;
            float pz = p[3 * i + 2] * 32.0f;
            if (fabsf(px) + fabsf(py) + fabsf(pz) == 0.0f) continue;
            float gxs = px + 32.0f, gys = py + 32.0f, gzs = pz + 32.0f;
            float lx = floorf(gxs), ly = floorf(gys), lz = floorf(gzs);
            int ix = (int)lx, iy = (int)ly, iz = (int)lz;
            if ((unsigned)ix > 63u) continue;   // match p1's binning filter
            accum_corners(S, ix, iy, iz, gxs - lx, gys - ly, gzs - lz, x0);
        }
    }
    __syncthreads();

    // Flush: cell i (= (xl*64+y)*64+z) = A[i] + (z>0 ? B[i-1] : 0), dequant.
    float* o = out + ((size_t)b * 64 + x0) * 4096;
    #pragma unroll
    for (int i = threadIdx.x; i < 2 * 4096; i += 1024) {
        int z = i & 63;
        unsigned int v = S[i] + (z ? S[ACCN + i - 1] : 0u);
        o[i] = (float)v * QINV;
    }
}

// ---- Fallback (exclusive-slab redundant scan) if workspace too small.
__global__ __launch_bounds__(1024) void gridding_slab(
    const float* __restrict__ pt, float* __restrict__ out)
{
    __shared__ float lds[SLABW * 64 * 64];
    const int blk = blockIdx.x;
    const int b   = blk >> 4;
    const int x0  = (blk & 15) * SLABW;
    float4* l4 = (float4*)lds;
    #pragma unroll
    for (int i = threadIdx.x; i < (SLABW * 64 * 64) / 4; i += 1024)
        l4[i] = make_float4(0.f, 0.f, 0.f, 0.f);
    __syncthreads();
    const float* p = pt + (size_t)b * NPTS * 3;
    for (int it = 0; it < NPTS / 1024; ++it) {
        int i = it * 1024 + threadIdx.x;
        float px = p[3 * i + 0] * 32.0f;
        float py = p[3 * i + 1] * 32.0f;
        float pz = p[3 * i + 2] * 32.0f;
        if (fabsf(px) + fabsf(py) + fabsf(pz) == 0.0f) continue;
        float lx = floorf(px), ly = floorf(py), lz = floorf(pz);
        float fx = px - lx, fy = py - ly, fz = pz - lz;
        int ix = (int)lx + 32, iy = (int)ly + 32, iz = (int)lz + 32;
        float wx[2] = {1.0f - fx, fx};
        float wy[2] = {1.0f - fy, fy};
        float wz[2] = {1.0f - fz, fz};
        #pragma unroll
        for (int di = 0; di < 2; ++di) {
            int xl = (ix + di) - x0;
            if ((unsigned)xl >= SLABW) continue;
            #pragma unroll
            for (int dj = 0; dj < 2; ++dj) {
                int yy = iy + dj;
                if ((unsigned)yy >= 64u) continue;
                float wxy = wx[di] * wy[dj];
                int basei = (xl * 64 + yy) * 64;
                #pragma unroll
                for (int dk = 0; dk < 2; ++dk) {
                    int zz = iz + dk;
                    if ((unsigned)zz >= 64u) continue;
                    atomicAdd(&lds[basei + zz], wxy * wz[dk]);
                }
            }
        }
    }
    __syncthreads();
    float4* o4 = (float4*)(out + ((size_t)b * 64 + x0) * 4096);
    #pragma unroll
    for (int i = threadIdx.x; i < (SLABW * 64 * 64) / 4; i += 1024)
        o4[i] = l4[i];
}

extern "C" void kernel_launch(void* const* d_in, const int* in_sizes, int n_in,
                              void* d_out, int out_size, void* d_ws, size_t ws_size,
                              hipStream_t stream) {
    const float* pt = (const float*)d_in[0];
    float* out = (float*)d_out;
    const int B = (in_sizes[0] / 3) / NPTS;   // 64

    const size_t nbuck = (size_t)B * NSLAB;           // 1024
    const size_t arr   = nbuck * SLOTS;
    const size_t need  = arr * sizeof(unsigned long long)
                       + nbuck * NCHUNK * sizeof(int);

    if (ws_size >= need) {
        unsigned long long* gp = (unsigned long long*)d_ws;
        int* bcnt = (int*)(gp + arr);
        p1_bin<<<B * NCHUNK, 512, 0, stream>>>(pt, gp, bcnt);
        p2_accum<<<(int)(nbuck * 2), 1024, 0, stream>>>(gp, bcnt, pt, out);
    } else {
        gridding_slab<<<B * NSLAB, 1024, 0, stream>>>(pt, out);
    }
}

// Round 4
// 159.885 us; speedup vs baseline: 1.2707x; 1.2707x over previous
//
#include <hip/hip_runtime.h>

// Gridding R9: p1 reverted to R7 (ballot experiment in R8 cost +40 µs on p1:
//   16-slab ballot loop ~200 VALU/64pts >> the ~4-way-serialized counter
//   atomics it replaced). p2 keeps R8's scnt LDS cache (82.4 -> 70.6 µs) and
//   adds register prefetch of all 8 slot u64s before the decode+atomic loop:
//   R8 proved p2 is partially load-latency-bound (removing in-loop count
//   reads alone gave -12 µs; ds_add_u64 is fire-and-forget so the only
//   remaining stall is vmcnt on each iteration's own gp[] load; 128 KB LDS
//   -> 1 block/CU -> only ~13 waves to hide it). Loads are unconditional
//   (slots always in-bounds), atomics predicated by the count check.
//   Dispatch accounting: fixed ~60 µs of harness reset/poison lives in the
//   timed graph (top-5 always p2; p1+X back-solves to p1~30, X~60).

#define NPTS   65536
#define NCHUNK 32
#define CHSZ   2048
#define NSLAB  16                  // p1 bucket slabs (4 planes)
#define SLABW  4
#define CCAP   256
#define SLOTS  (NCHUNK * CCAP)     // 8192 slots per bucket
#define ACCN   16384               // 2 planes * 64 * 64 u32 per accumulator
#define QSCALE 262144.0f           // 2^18 weight quant
#define QINV   (1.0f / 262144.0f)
#define CMASK  0x1FFFFFu           // 21-bit coordinate field
#define FSCALE 32768.0f            // 2^15 coordinate quant
#define FINV   (1.0f / 32768.0f)

// ---------------- Phase 1: identical to R7 (the fast one) ----------------
__global__ __launch_bounds__(512) void p1_bin(
    const float* __restrict__ pt,
    unsigned long long* __restrict__ gp,
    int* __restrict__ bcnt)
{
    __shared__ unsigned long long spk[NSLAB * CCAP];   // 32 KB
    __shared__ int cnt[NSLAB];
    if (threadIdx.x < NSLAB) cnt[threadIdx.x] = 0;
    __syncthreads();

    const int blk = blockIdx.x;
    const int b = blk >> 5;
    const int c = blk & 31;
    const float* p = pt + ((size_t)b * NPTS + (size_t)c * CHSZ) * 3;

    #pragma unroll
    for (int k = 0; k < CHSZ / 512; ++k) {
        int li = k * 512 + threadIdx.x;
        float px = p[3 * li + 0] * 32.0f;
        float py = p[3 * li + 1] * 32.0f;
        float pz = p[3 * li + 2] * 32.0f;
        if (fabsf(px) + fabsf(py) + fabsf(pz) == 0.0f) continue;
        // grid-space [0,64) fixed point, round-to-nearest, clamped to the
        // 21-bit field (prevents cross-field carry for boundary values).
        unsigned ux = min(__float2uint_rn((px + 32.0f) * FSCALE), CMASK);
        unsigned uy = min(__float2uint_rn((py + 32.0f) * FSCALE), CMASK);
        unsigned uz = min(__float2uint_rn((pz + 32.0f) * FSCALE), CMASK);
        int ix = (int)(ux >> 15);            // 0..63 by construction
        unsigned long long pk =
            (unsigned long long)ux | ((unsigned long long)uy << 21)
                                   | ((unsigned long long)uz << 42);
        int s0 = ix >> 2;
        int pos = atomicAdd(&cnt[s0], 1);
        if (pos < CCAP) spk[s0 * CCAP + pos] = pk;
        if ((ix & 3) == 3 && ix < 63) {
            int pos1 = atomicAdd(&cnt[s0 + 1], 1);
            if (pos1 < CCAP) spk[(s0 + 1) * CCAP + pos1] = pk;
        }
    }
    __syncthreads();

    // Flush only the counted slots (garbage slots never touch HBM).
    #pragma unroll
    for (int i = threadIdx.x; i < NSLAB * CCAP; i += 512) {
        int s = i >> 8, e = i & 255;
        if (e < min(cnt[s], CCAP)) {
            size_t d = ((size_t)((b * NSLAB + s) * NCHUNK + c)) * CCAP + e;
            gp[d] = spk[i];
        }
    }
    if (threadIdx.x < NSLAB)
        bcnt[(b * NSLAB + threadIdx.x) * NCHUNK + c] = min(cnt[threadIdx.x], CCAP);
}

// Shared corner accumulation (packed u64 LDS atomics), grid-space coords.
//   S[0..ACCN)      = A: cell (xl,y,z) at (xl*64+y)*64+z   (z-even u64 pairs)
//   S[ACCN..2*ACCN) = B: shifted pairs (z-odd), B[cb+z-1],B[cb+z]
__device__ __forceinline__ void accum_corners(
    unsigned int* S, int ix, int iy, int iz,
    float fx, float fy, float fz, int x0)
{
    if ((unsigned)iz > 63u) return;     // OOB z (garbage guard)

    float wx[2] = {1.0f - fx, fx};
    float wy[2] = {1.0f - fy, fy};
    float wz0 = 1.0f - fz, wz1 = fz;

    const int odd = iz & 1;
    const int zoff = odd ? (ACCN + iz - 1) : iz;   // both branches 8B-aligned
    const bool hi_ok = (iz != 63);                 // cell iz+1==64 OOB -> add 0

    #pragma unroll
    for (int di = 0; di < 2; ++di) {
        int xl = ix + di - x0;              // sub-slab-local x
        if ((unsigned)xl >= 2u) continue;
        #pragma unroll
        for (int dj = 0; dj < 2; ++dj) {
            int yy = iy + dj;
            if ((unsigned)yy >= 64u) continue;
            float wxy = wx[di] * wy[dj];
            unsigned int q0 = __float2uint_rn(wxy * wz0 * QSCALE);
            unsigned int q1 = hi_ok ? __float2uint_rn(wxy * wz1 * QSCALE) : 0u;
            int cb = (xl * 64 + yy) * 64;
            unsigned long long pk =
                (unsigned long long)q0 | ((unsigned long long)q1 << 32);
            atomicAdd((unsigned long long*)&S[cb + zoff], pk);  // ds_add_u64
        }
    }
}

// ---------------- Phase 2: 2-plane sub-slab, packed u64 LDS atomics -------
__global__ __launch_bounds__(1024) void p2_accum(
    const unsigned long long* __restrict__ gp, const int* __restrict__ bcnt,
    const float* __restrict__ pt, float* __restrict__ out)
{
    __shared__ unsigned int S[2 * ACCN];
    __shared__ int scnt[NCHUNK];
    __shared__ int rescan;

    const int pb = blockIdx.x >> 1;     // parent bucket (b*16 + s)
    const int h  = blockIdx.x & 1;      // which half of the 4-wide slab
    const int b  = pb >> 4;
    const int s  = pb & 15;
    const int x0 = s * SLABW + h * 2;   // my 2 planes: x0, x0+1

    if (threadIdx.x == 0) rescan = 0;
    if (threadIdx.x < NCHUNK)
        scnt[threadIdx.x] = bcnt[pb * NCHUNK + threadIdx.x];
    uint4* s4 = (uint4*)S;
    #pragma unroll
    for (int i = threadIdx.x; i < (2 * ACCN) / 4; i += 1024)
        s4[i] = make_uint4(0u, 0u, 0u, 0u);
    __syncthreads();

    // Saturation / sanity check: CCAP sentinel (p1 dropped points) or
    // garbage counts -> this block redoes its sub-slab from raw points.
    if (threadIdx.x < NCHUNK) {
        if ((unsigned)scnt[threadIdx.x] >= (unsigned)CCAP) rescan = 1;
    }
    __syncthreads();

    if (!rescan) {
        // ---- fast path: prefetch ALL 8 slots into registers, then
        //      decode+atomic with no exposed load latency. Loads are
        //      unconditional (slots always in-bounds in ws); the count
        //      predicate gates the atomics only.
        const size_t base = (size_t)pb * SLOTS;

        unsigned long long v[SLOTS / 1024];
        bool ok[SLOTS / 1024];
        #pragma unroll
        for (int i = 0; i < SLOTS / 1024; ++i) {
            int t = i * 1024 + threadIdx.x;
            v[i]  = gp[base + t];
            ok[i] = (t & 255) < scnt[t >> 8];
        }

        #pragma unroll
        for (int i = 0; i < SLOTS / 1024; ++i) {
            if (!ok[i]) continue;
            unsigned long long pk = v[i];
            unsigned ux = (unsigned)pk & CMASK;
            unsigned uy = (unsigned)(pk >> 21) & CMASK;
            unsigned uz = (unsigned)(pk >> 42) & CMASK;
            accum_corners(S, (int)(ux >> 15), (int)(uy >> 15), (int)(uz >> 15),
                          (float)(ux & 32767u) * FINV,
                          (float)(uy & 32767u) * FINV,
                          (float)(uz & 32767u) * FINV, x0);
        }
    } else {
        // ---- self-healing path: exclusive scan of batch b's raw points ----
        const float* p = pt + (size_t)b * NPTS * 3;
        for (int i = threadIdx.x; i < NPTS; i += 1024) {
            float px = p[3 * i + 0] * 32.0f;
            float py = p[3 * i + 1] * 32.0f;
            float pz = p[3 * i + 2] * 32.0f;
            if (fabsf(px) + fabsf(py) + fabsf(pz) == 0.0f) continue;
            float gxs = px + 32.0f, gys = py + 32.0f, gzs = pz + 32.0f;
            float lx = floorf(gxs), ly = floorf(gys), lz = floorf(gzs);
            int ix = (int)lx, iy = (int)ly, iz = (int)lz;
            if ((unsigned)ix > 63u) continue;   // match p1's binning filter
            accum_corners(S, ix, iy, iz, gxs - lx, gys - ly, gzs - lz, x0);
        }
    }
    __syncthreads();

    // Flush: cell i (= (xl*64+y)*64+z) = A[i] + (z>0 ? B[i-1] : 0), dequant.
    float* o = out + ((size_t)b * 64 + x0) * 4096;
    #pragma unroll
    for (int i = threadIdx.x; i < 2 * 4096; i += 1024) {
        int z = i & 63;
        unsigned int v2 = S[i] + (z ? S[ACCN + i - 1] : 0u);
        o[i] = (float)v2 * QINV;
    }
}

// ---- Fallback (exclusive-slab redundant scan) if workspace too small.
__global__ __launch_bounds__(1024) void gridding_slab(
    const float* __restrict__ pt, float* __restrict__ out)
{
    __shared__ float lds[SLABW * 64 * 64];
    const int blk = blockIdx.x;
    const int b   = blk >> 4;
    const int x0  = (blk & 15) * SLABW;
    float4* l4 = (float4*)lds;
    #pragma unroll
    for (int i = threadIdx.x; i < (SLABW * 64 * 64) / 4; i += 1024)
        l4[i] = make_float4(0.f, 0.f, 0.f, 0.f);
    __syncthreads();
    const float* p = pt + (size_t)b * NPTS * 3;
    for (int it = 0; it < NPTS / 1024; ++it) {
        int i = it * 1024 + threadIdx.x;
        float px = p[3 * i + 0] * 32.0f;
        float py = p[3 * i + 1] * 32.0f;
        float pz = p[3 * i + 2] * 32.0f;
        if (fabsf(px) + fabsf(py) + fabsf(pz) == 0.0f) continue;
        float lx = floorf(px), ly = floorf(py), lz = floorf(pz);
        float fx = px - lx, fy = py - ly, fz = pz - lz;
        int ix = (int)lx + 32, iy = (int)ly + 32, iz = (int)lz + 32;
        float wx[2] = {1.0f - fx, fx};
        float wy[2] = {1.0f - fy, fy};
        float wz[2] = {1.0f - fz, fz};
        #pragma unroll
        for (int di = 0; di < 2; ++di) {
            int xl = (ix + di) - x0;
            if ((unsigned)xl >= SLABW) continue;
            #pragma unroll
            for (int dj = 0; dj < 2; ++dj) {
                int yy = iy + dj;
                if ((unsigned)yy >= 64u) continue;
                float wxy = wx[di] * wy[dj];
                int basei = (xl * 64 + yy) * 64;
                #pragma unroll
                for (int dk = 0; dk < 2; ++dk) {
                    int zz = iz + dk;
                    if ((unsigned)zz >= 64u) continue;
                    atomicAdd(&lds[basei + zz], wxy * wz[dk]);
                }
            }
        }
    }
    __syncthreads();
    float4* o4 = (float4*)(out + ((size_t)b * 64 + x0) * 4096);
    #pragma unroll
    for (int i = threadIdx.x; i < (SLABW * 64 * 64) / 4; i += 1024)
        o4[i] = l4[i];
}

extern "C" void kernel_launch(void* const* d_in, const int* in_sizes, int n_in,
                              void* d_out, int out_size, void* d_ws, size_t ws_size,
                              hipStream_t stream) {
    const float* pt = (const float*)d_in[0];
    float* out = (float*)d_out;
    const int B = (in_sizes[0] / 3) / NPTS;   // 64

    const size_t nbuck = (size_t)B * NSLAB;           // 1024
    const size_t arr   = nbuck * SLOTS;
    const size_t need  = arr * sizeof(unsigned long long)
                       + nbuck * NCHUNK * sizeof(int);

    if (ws_size >= need) {
        unsigned long long* gp = (unsigned long long*)d_ws;
        int* bcnt = (int*)(gp + arr);
        p1_bin<<<B * NCHUNK, 512, 0, stream>>>(pt, gp, bcnt);
        p2_accum<<<(int)(nbuck * 2), 1024, 0, stream>>>(gp, bcnt, pt, out);
    } else {
        gridding_slab<<<B * NSLAB, 1024, 0, stream>>>(pt, out);
    }
}